// Round 6
// baseline (186.533 us; speedup 1.0000x reference)
//
#include <hip/hip_runtime.h>
#include <math.h>

#define K_CB 1024
#define D_Z  64
#define MT   32                  // rows per block
#define NTOT 65536
#define NBLK (NTOT / MT)         // 2048

typedef __attribute__((ext_vector_type(8)))  short s16x8;
typedef __attribute__((ext_vector_type(4)))  short s16x4;
typedef __attribute__((ext_vector_type(4)))  float f32x4;
typedef __attribute__((ext_vector_type(16))) float f32x16;

// ws layout (bytes)
#define WS_CB16  0        // [1024][64] bf16
#define WS_CBT16 131072   // [64][1024] bf16
#define WS_NWSQC 262144   // [1024] f32  (-w*||c||^2)
#define WS_PART  266240   // [2048] f32 block partials

__device__ __forceinline__ unsigned short f2b(float f) {
  unsigned int u = __float_as_uint(f);
  u += 0x7fffu + ((u >> 16) & 1u);
  return (unsigned short)(u >> 16);
}

__global__ void vq_prep(const float* __restrict__ cb, const float* __restrict__ lvq,
                        unsigned char* __restrict__ wsb) {
  unsigned short* cb16  = (unsigned short*)(wsb + WS_CB16);
  unsigned short* cbT16 = (unsigned short*)(wsb + WS_CBT16);
  float* nwsqc = (float*)(wsb + WS_NWSQC);
  const float w = 0.5f / fmaxf(1.0f + __expf(lvq[0]), 1e-10f);
  const int tid = threadIdx.x;
  const int k  = blockIdx.x * 16 + (tid >> 4);
  const int d0 = (tid & 15) * 4;
  const f32x4 v = *(const f32x4*)(cb + k * D_Z + d0);
  s16x4 b4;
  #pragma unroll
  for (int i = 0; i < 4; i++) b4[i] = (short)f2b(v[i]);
  *(s16x4*)(cb16 + k * D_Z + d0) = b4;
  #pragma unroll
  for (int i = 0; i < 4; i++) cbT16[(d0 + i) * K_CB + k] = (unsigned short)b4[i];
  float s = v[0]*v[0] + v[1]*v[1] + v[2]*v[2] + v[3]*v[3];
  #pragma unroll
  for (int off = 1; off < 16; off <<= 1) s += __shfl_xor(s, off);
  if ((tid & 15) == 0) nwsqc[k] = -w * s;
}

__global__ __launch_bounds__(512, 2)
void vq_main(const float* __restrict__ x, const float* __restrict__ gum,
             const float* __restrict__ lvq, unsigned char* __restrict__ wsb,
             float* __restrict__ out) {
  __shared__ __align__(16) unsigned short xa[MT * D_Z];   // XOR-swizzled [m][d]
  __shared__ __align__(16) unsigned short es[MT * K_CB];  // XOR-swizzled [m][k]
  __shared__ __align__(16) float stats[8][MT][4];         // m1,s1,A,m2 per wave/row
  __shared__ __align__(16) float s2s[8][MT];
  __shared__ float kldrow[MT];
  __shared__ float wred[8];

  const int tid  = threadIdx.x;
  const int w    = tid >> 6;           // wave 0..7, owns codes [w*128, +128)
  const int lane = tid & 63;
  const int m32  = lane & 31;          // output row (MFMA col)
  const int hi   = lane >> 5;
  const int bid  = blockIdx.x;
  const int blk  = ((bid & 7) << 8) | (bid >> 3);   // bijective XCD remap
  const int row0 = blk * MT;
  const int bidx = row0 >> 10;
  const int rem0 = row0 & 1023;
  const int kw0  = w << 7;

  const float wq = 0.5f / fmaxf(1.0f + __expf(lvq[0]), 1e-10f);
  const float w2 = 2.0f * wq;

  const unsigned short* cb16  = (const unsigned short*)(wsb + WS_CB16);
  const unsigned short* cbT16 = (const unsigned short*)(wsb + WS_CBT16);
  const float* nwsqc = (const float*)(wsb + WS_NWSQC);

  // ---- P0: stage x tile [32 rows][64 d] bf16, XOR-swizzled rows ----
  {
    const int m = tid & 31, dg = tid >> 5;
    #pragma unroll
    for (int i = 0; i < 4; i++) {
      const int d = dg + 16 * i;
      const float v = x[((bidx * D_Z + d) << 10) + rem0 + m];
      xa[(m * D_Z + d) ^ ((m & 7) << 3)] = f2b(v);
    }
  }
  __syncthreads();

  // ---- GEMM1 (swapped, 32x32x16): D[code][m], wave codes kw0..+128 ----
  // Deep ILP: A-frags in 2 batches of 8; gumbel batches issued under compute.
  f32x16 acc[4];
  #pragma unroll
  for (int t = 0; t < 4; t++)
    #pragma unroll
    for (int r = 0; r < 16; r++) acc[t][r] = 0.f;

  const float* gp = gum + ((size_t)(row0 + m32) << 10) + kw0 + hi * 4;
  const unsigned short* ap = cb16 + (kw0 + m32) * D_Z + hi * 8;  // + t*2048 + kb*16
  f32x4 gA[8], gB[8];
  s16x8 bx[4], af[8];

  #pragma unroll
  for (int kb = 0; kb < 4; kb++) {
    const int byteoff = (m32 * 128 + kb * 32 + hi * 16) ^ ((m32 & 7) << 4);
    bx[kb] = *(const s16x8*)((const unsigned char*)xa + byteoff);
  }
  // batch A loads: tiles 0,1 (8 frags)
  #pragma unroll
  for (int i = 0; i < 8; i++) af[i] = *(const s16x8*)(ap + (i >> 2) * 2048 + (i & 3) * 16);
  // gumbel batch A issued now: consumed ~1500cy later
  #pragma unroll
  for (int u = 0; u < 8; u++) gA[u] = *(const f32x4*)(gp + (u >> 2) * 32 + (u & 3) * 8);
  // MFMA tiles 0,1
  #pragma unroll
  for (int i = 0; i < 8; i++)
    acc[i >> 2] = __builtin_amdgcn_mfma_f32_32x32x16_bf16(af[i], bx[i & 3], acc[i >> 2], 0, 0, 0);
  // batch B loads: tiles 2,3
  #pragma unroll
  for (int i = 0; i < 8; i++) af[i] = *(const s16x8*)(ap + (2 + (i >> 2)) * 2048 + (i & 3) * 16);
  // gumbel batch B issued now: consumed ~700cy later
  #pragma unroll
  for (int u = 0; u < 8; u++) gB[u] = *(const f32x4*)(gp + 64 + (u >> 2) * 32 + (u & 3) * 8);
  // MFMA tiles 2,3
  #pragma unroll
  for (int i = 0; i < 8; i++)
    acc[2 + (i >> 2)] = __builtin_amdgcn_mfma_f32_32x32x16_bf16(af[i], bx[i & 3], acc[2 + (i >> 2)], 0, 0, 0);

  // ---- logits: acc = w2*cross + (-w*||c||^2); per-wave row max m1 ----
  float m1 = -3.4e38f;
  #pragma unroll
  for (int t = 0; t < 4; t++) {
    #pragma unroll
    for (int q = 0; q < 4; q++) {
      const f32x4 nw = *(const f32x4*)(nwsqc + kw0 + t * 32 + q * 8 + hi * 4);
      #pragma unroll
      for (int i = 0; i < 4; i++) {
        acc[t][q * 4 + i] = fmaf(w2, acc[t][q * 4 + i], nw[i]);
        m1 = fmaxf(m1, acc[t][q * 4 + i]);
      }
    }
  }
  m1 = fmaxf(m1, __shfl_xor(m1, 32));

  // ---- s1 / A pass ----
  float s1 = 0.f, Aa = 0.f;
  #pragma unroll
  for (int t = 0; t < 4; t++) {
    #pragma unroll
    for (int r = 0; r < 16; r++) {
      const float u = acc[t][r] - m1;
      const float e = __expf(u);
      s1 += e;
      Aa = fmaf(u, e, Aa);
    }
  }
  s1 += __shfl_xor(s1, 32);
  Aa += __shfl_xor(Aa, 32);

  // ---- z = 2*(logit+g); per-wave m2 ----
  float m2 = -3.4e38f;
  #pragma unroll
  for (int u = 0; u < 8; u++) {
    const int t = u >> 2, q = u & 3;
    #pragma unroll
    for (int i = 0; i < 4; i++) {
      const float z = 2.0f * (acc[t][q * 4 + i] + gA[u][i]);
      acc[t][q * 4 + i] = z;
      m2 = fmaxf(m2, z);
    }
  }
  #pragma unroll
  for (int u = 0; u < 8; u++) {
    const int t = 2 + (u >> 2), q = u & 3;
    #pragma unroll
    for (int i = 0; i < 4; i++) {
      const float z = 2.0f * (acc[t][q * 4 + i] + gB[u][i]);
      acc[t][q * 4 + i] = z;
      m2 = fmaxf(m2, z);
    }
  }
  m2 = fmaxf(m2, __shfl_xor(m2, 32));
  if (hi == 0) {
    f32x4 st = {m1, s1, Aa, m2};
    *(f32x4*)&stats[w][m32][0] = st;
  }
  __syncthreads();

  // ---- cross-wave: global row max M2; wave 0 computes kld_discrete rows ----
  float M2 = -3.4e38f;
  {
    f32x4 st[8];
    #pragma unroll
    for (int q = 0; q < 8; q++) {
      st[q] = *(const f32x4*)&stats[q][m32][0];
      M2 = fmaxf(M2, st[q][3]);
    }
    if (w == 0) {
      float M1 = -3.4e38f;
      #pragma unroll
      for (int q = 0; q < 8; q++) M1 = fmaxf(M1, st[q][0]);
      float s1g = 0.f, Ag = 0.f;
      #pragma unroll
      for (int q = 0; q < 8; q++) {
        const float dm = st[q][0] - M1;
        const float c  = __expf(dm);
        s1g += c * st[q][1];
        Ag = fmaf(c, fmaf(dm, st[q][1], st[q][2]), Ag);
      }
      if (hi == 0) kldrow[m32] = Ag / s1g - __logf(s1g);
    }
  }

  // ---- encode e = exp(z - M2), bf16 pairs -> es ----
  float s2 = 0.f;
  #pragma unroll
  for (int t = 0; t < 4; t++) {
    #pragma unroll
    for (int q = 0; q < 4; q++) {
      float e[4];
      #pragma unroll
      for (int i = 0; i < 4; i++) {
        e[i] = __expf(acc[t][q * 4 + i] - M2);
        s2 += e[i];
      }
      const unsigned int p0 = (unsigned int)f2b(e[0]) | ((unsigned int)f2b(e[1]) << 16);
      const unsigned int p1 = (unsigned int)f2b(e[2]) | ((unsigned int)f2b(e[3]) << 16);
      const unsigned long long pk = (unsigned long long)p0 | ((unsigned long long)p1 << 32);
      const int byteoff = (m32 * 2048 + (kw0 + t * 32 + q * 8 + hi * 4) * 2) ^ ((m32 & 7) << 4);
      *(unsigned long long*)((unsigned char*)es + byteoff) = pk;
    }
  }
  s2 += __shfl_xor(s2, 32);
  if (hi == 0) s2s[w][m32] = s2;
  __syncthreads();

  // ---- GEMM2 (swapped, 16x16x32): wave -> (d-block w>>1, m-block w&1) ----
  const int m16 = lane & 15, g = lane >> 4;
  const int db = w >> 1, mb = w & 1;
  const int mrow = mb * 16 + m16;
  float s2g = 0.f;
  #pragma unroll
  for (int q = 0; q < 8; q++) s2g += s2s[q][mrow];
  const float inv2 = 1.0f / s2g;

  // epilogue x loads hoisted before GEMM2 (consumed after)
  int offs[4];
  float xv[4];
  #pragma unroll
  for (int r = 0; r < 4; r++) {
    const int d = db * 16 + g * 4 + r;
    offs[r] = ((bidx * D_Z + d) << 10) + rem0 + mrow;
    xv[r] = x[offs[r]];
  }

  f32x4 qacc = (f32x4){0.f, 0.f, 0.f, 0.f};
  {
    const unsigned short* a2p = cbT16 + (db * 16 + m16) * K_CB + g * 8;
    const unsigned char* esb = (const unsigned char*)es;
    s16x8 a2b[2][4];
    #pragma unroll
    for (int j = 0; j < 4; j++) a2b[0][j] = *(const s16x8*)(a2p + j * 32);
    #pragma unroll
    for (int c = 0; c < 8; c++) {
      if (c < 7) {
        #pragma unroll
        for (int j = 0; j < 4; j++)
          a2b[(c + 1) & 1][j] = *(const s16x8*)(a2p + ((c + 1) * 4 + j) * 32);
      }
      #pragma unroll
      for (int j = 0; j < 4; j++) {
        const int kc = c * 4 + j;
        const int byteoff = (mrow * 2048 + kc * 64 + g * 16) ^ ((m16 & 7) << 4);
        const s16x8 b2 = *(const s16x8*)(esb + byteoff);
        qacc = __builtin_amdgcn_mfma_f32_16x16x32_bf16(a2b[c & 1][j], b2, qacc, 0, 0, 0);
      }
    }
  }

  // ---- epilogue: normalize, write, kld_continuous ----
  float kca = 0.f;
  #pragma unroll
  for (int r = 0; r < 4; r++) {
    const float qv = qacc[r] * inv2;
    out[offs[r]] = qv;
    const float dx = xv[r] - qv;
    kca = fmaf(dx, dx, kca);
  }
  #pragma unroll
  for (int off = 1; off < 64; off <<= 1) kca += __shfl_xor(kca, off);
  if (lane == 0) wred[w] = kca;
  __syncthreads();
  if (tid == 0) {
    float tot = 0.f;
    #pragma unroll
    for (int q = 0; q < 8; q++) tot += wred[q];
    tot *= wq;
    #pragma unroll
    for (int i = 0; i < MT; i++) tot += kldrow[i];
    ((float*)(wsb + WS_PART))[blk] = tot;
  }
}

__global__ void vq_reduce(const unsigned char* __restrict__ wsb, float* __restrict__ out) {
  __shared__ float red[256];
  const float* part = (const float*)(wsb + WS_PART);
  const int t = threadIdx.x;
  float s = 0.f;
  for (int i = t; i < NBLK; i += 256) s += part[i];
  red[t] = s;
  __syncthreads();
  for (int st = 128; st > 0; st >>= 1) {
    if (t < st) red[t] += red[t + st];
    __syncthreads();
  }
  if (t == 0) out[NTOT * D_Z] = red[0] * (1.0f / 64.0f);
}

extern "C" void kernel_launch(void* const* d_in, const int* in_sizes, int n_in,
                              void* d_out, int out_size, void* d_ws, size_t ws_size,
                              hipStream_t stream) {
  const float* x   = (const float*)d_in[0];
  const float* cb  = (const float*)d_in[1];
  const float* lvq = (const float*)d_in[2];
  const float* gum = (const float*)d_in[3];
  float* out = (float*)d_out;
  unsigned char* wsb = (unsigned char*)d_ws;

  hipLaunchKernelGGL(vq_prep,   dim3(64),   dim3(256), 0, stream, cb, lvq, wsb);
  hipLaunchKernelGGL(vq_main,   dim3(NBLK), dim3(512), 0, stream, x, gum, lvq, wsb, out);
  hipLaunchKernelGGL(vq_reduce, dim3(1),    dim3(256), 0, stream, wsb, out);
}